// Round 18
// baseline (313.290 us; speedup 1.0000x reference)
//
#include <hip/hip_runtime.h>
#include <stdint.h>

#define WINDOW 2048
#define EMBED  1024
#define BATCH  8
#define MTOT   (BATCH*WINDOW)   // 16384 rows total

typedef unsigned short u16;
typedef __bf16 bf16x8 __attribute__((ext_vector_type(8)));
typedef float  f32x4  __attribute__((ext_vector_type(4)));

#define BK 64
#define KSCALE 0.04508422717564447f   /* log2(e)/32 folded into stored K */

// ---- 256x256 tile, 8 waves (2M x 4N -> 128x64/wave), kk-split halves ----
#define BM2 256
#define BN2 256
#define HALF2 8192    // kk-half: 256r x 32c (16 KiB); 8 halves = 128 KiB
#define PLD  260      // padded LDS row (u16) for the P-bounce epilogue

// ---- 128x256 rect core (spd tail half-jobs): 8 waves 2Mx4N -> 64x64/wave ----
#define AHALFR 4096   // A kk-half: 128r x 32c (8 KiB)
#define BHALFR 8192   // B kk-half: 256r x 32c (16 KiB)  -> total 96 KiB

#define WAITVM4 asm volatile("s_waitcnt vmcnt(4)" ::: "memory")
#define WAITVM3 asm volatile("s_waitcnt vmcnt(3)" ::: "memory")
#define WAITVM0 asm volatile("s_waitcnt vmcnt(0)" ::: "memory")
#define SBAR    __builtin_amdgcn_s_barrier()

__device__ __forceinline__ u16 f2bf(float f) {
  union { float f; unsigned u; } a; a.f = f;
  unsigned r = a.u + 0x7FFF + ((a.u >> 16) & 1);   // RNE
  return (u16)(r >> 16);
}
__device__ __forceinline__ float bf2f(u16 u) {
  union { unsigned u; float f; } a; a.u = ((unsigned)u) << 16;
  return a.f;
}

__device__ __forceinline__ void gload16(const u16* g, u16* l) {
  __builtin_amdgcn_global_load_lds(
      (const __attribute__((address_space(1))) unsigned int*)g,
      (__attribute__((address_space(3))) unsigned int*)l, 16, 0, 0);
}

// Swizzle (rule #21): LDS dest LINEAR slot f = r*4 + c; global SOURCE chunk is
// c ^ ((r>>1)&3) (involution) so a read at slot hi^((r>>1)&3) sees logical
// chunk hi.  ds_read_b128 lands 2-way bank-aliased only (free, m136).

// ============ 256x256 core: acc[8][4], 2 phases/K-tile (32 MFMA each) ============
__device__ __forceinline__ void gemm256(
    const u16* __restrict__ A, int lda,
    const u16* __restrict__ B, int ldb,
    int nt, u16* lds, f32x4 acc[8][4])
{
  const int tid  = threadIdx.x;
  const int lane = tid & 63;
  const int wid  = tid >> 6;
  const int wm   = (wid >> 2) * 128;
  const int wn   = (wid & 3) * 64;
  const int lrow = lane & 15;
  const int hi   = lane >> 4;
  u16* dA = lds;
  u16* dB = lds + 4 * HALF2;

  int aoff[8], boff[4];
  #pragma unroll
  for (int mi = 0; mi < 8; ++mi) {
    int r = wm + mi * 16 + lrow;
    aoff[mi] = r * 32 + ((hi ^ ((r >> 1) & 3)) << 3);
  }
  #pragma unroll
  for (int ni = 0; ni < 4; ++ni) {
    int r = wn + ni * 16 + lrow;
    boff[ni] = r * 32 + ((hi ^ ((r >> 1) & 3)) << 3);
  }

  const int f0 = tid, f1 = 512 + tid;
  const int r0 = f0 >> 2, r1 = f1 >> 2;
  const int c0 = (((f0 & 3) ^ ((r0 >> 1) & 3)) << 3);
  const int c1 = (((f1 & 3) ^ ((r1 >> 1) & 3)) << 3);
  const u16* pA0 = A + (size_t)r0 * lda + c0;
  const u16* pA1 = A + (size_t)r1 * lda + c1;
  const u16* pB0 = B + (size_t)r0 * ldb + c0;
  const u16* pB1 = B + (size_t)r1 * ldb + c1;
  const int d0 = f0 * 8, d1 = f1 * 8;

  gload16(pA0,      dA + d0);         gload16(pA1,      dA + d1);
  gload16(pB0,      dB + d0);         gload16(pB1,      dB + d1);
  gload16(pA0 + 32, dA + HALF2 + d0); gload16(pA1 + 32, dA + HALF2 + d1);
  gload16(pB0 + 32, dB + HALF2 + d0); gload16(pB1 + 32, dB + HALF2 + d1);
  pA0 += BK; pA1 += BK; pB0 += BK; pB1 += BK;
  WAITVM4;
  SBAR;

  for (int t = 0; t < nt; ++t) {
    const int cb = (t & 1) * 2;
    const int nb = ((t + 1) & 1) * 2;
    u16* LA0 = dA + cb * HALF2;  u16* LA1 = LA0 + HALF2;
    u16* LB0 = dB + cb * HALF2;  u16* LB1 = LB0 + HALF2;
    const bool s = (t + 1) < nt;
    bf16x8 av[8], bv[4];

    #pragma unroll
    for (int mi = 0; mi < 8; ++mi) av[mi] = *(const bf16x8*)(LA0 + aoff[mi]);
    #pragma unroll
    for (int ni = 0; ni < 4; ++ni) bv[ni] = *(const bf16x8*)(LB0 + boff[ni]);
    if (s) {
      gload16(pA0, dA + nb * HALF2 + d0); gload16(pA1, dA + nb * HALF2 + d1);
      gload16(pB0, dB + nb * HALF2 + d0); gload16(pB1, dB + nb * HALF2 + d1);
    }
    __builtin_amdgcn_s_setprio(1);
    #pragma unroll
    for (int mi = 0; mi < 8; ++mi)
      #pragma unroll
      for (int ni = 0; ni < 4; ++ni)
        acc[mi][ni] = __builtin_amdgcn_mfma_f32_16x16x32_bf16(av[mi], bv[ni], acc[mi][ni], 0, 0, 0);
    __builtin_amdgcn_s_setprio(0);
    if (s) { WAITVM4; } else { WAITVM0; }
    SBAR;

    #pragma unroll
    for (int mi = 0; mi < 8; ++mi) av[mi] = *(const bf16x8*)(LA1 + aoff[mi]);
    #pragma unroll
    for (int ni = 0; ni < 4; ++ni) bv[ni] = *(const bf16x8*)(LB1 + boff[ni]);
    if (s) {
      gload16(pA0 + 32, dA + nb * HALF2 + HALF2 + d0); gload16(pA1 + 32, dA + nb * HALF2 + HALF2 + d1);
      gload16(pB0 + 32, dB + nb * HALF2 + HALF2 + d0); gload16(pB1 + 32, dB + nb * HALF2 + HALF2 + d1);
      pA0 += BK; pA1 += BK; pB0 += BK; pB1 += BK;
    }
    __builtin_amdgcn_s_setprio(1);
    #pragma unroll
    for (int mi = 0; mi < 8; ++mi)
      #pragma unroll
      for (int ni = 0; ni < 4; ++ni)
        acc[mi][ni] = __builtin_amdgcn_mfma_f32_16x16x32_bf16(av[mi], bv[ni], acc[mi][ni], 0, 0, 0);
    __builtin_amdgcn_s_setprio(0);
    if (s) { WAITVM4; }
    SBAR;
  }
}

// ===== 128x256 rect core (verified in R5): acc[4][4], 2 phases/K-tile =====
__device__ __forceinline__ void gemm_rect(
    const u16* __restrict__ A, int lda,
    const u16* __restrict__ B, int ldb,
    int nt, u16* lds, f32x4 acc[4][4])
{
  const int tid  = threadIdx.x;
  const int lane = tid & 63;
  const int wid  = tid >> 6;
  const int wm   = (wid >> 2) * 64;   // 0/64
  const int wn   = (wid & 3) * 64;    // 0..192
  const int lrow = lane & 15;
  const int hi   = lane >> 4;
  u16* dA = lds;
  u16* dB = lds + 4 * AHALFR;

  int aoff[4], boff[4];
  #pragma unroll
  for (int mi = 0; mi < 4; ++mi) {
    int r = wm + mi * 16 + lrow;
    aoff[mi] = r * 32 + ((hi ^ ((r >> 1) & 3)) << 3);
  }
  #pragma unroll
  for (int ni = 0; ni < 4; ++ni) {
    int r = wn + ni * 16 + lrow;
    boff[ni] = r * 32 + ((hi ^ ((r >> 1) & 3)) << 3);
  }

  const int fa = tid;
  const int fb0 = tid, fb1 = 512 + tid;
  const int ra = fa >> 2, rb0 = fb0 >> 2, rb1 = fb1 >> 2;
  const int ca  = (((fa  & 3) ^ ((ra  >> 1) & 3)) << 3);
  const int cb0 = (((fb0 & 3) ^ ((rb0 >> 1) & 3)) << 3);
  const int cb1 = (((fb1 & 3) ^ ((rb1 >> 1) & 3)) << 3);
  const u16* pA  = A + (size_t)ra  * lda + ca;
  const u16* pB0 = B + (size_t)rb0 * ldb + cb0;
  const u16* pB1 = B + (size_t)rb1 * ldb + cb1;
  const int da = fa * 8, db0 = fb0 * 8, db1 = fb1 * 8;

  gload16(pA,       dA + da);
  gload16(pB0,      dB + db0);          gload16(pB1,      dB + db1);
  gload16(pA + 32,  dA + AHALFR + da);
  gload16(pB0 + 32, dB + BHALFR + db0); gload16(pB1 + 32, dB + BHALFR + db1);
  pA += BK; pB0 += BK; pB1 += BK;
  WAITVM3;
  SBAR;

  for (int t = 0; t < nt; ++t) {
    const int cb = (t & 1) * 2;
    const int nb = ((t + 1) & 1) * 2;
    u16* LA0 = dA + cb * AHALFR;  u16* LA1 = LA0 + AHALFR;
    u16* LB0 = dB + cb * BHALFR;  u16* LB1 = LB0 + BHALFR;
    const bool s = (t + 1) < nt;
    bf16x8 av[4], bv[4];

    #pragma unroll
    for (int mi = 0; mi < 4; ++mi) av[mi] = *(const bf16x8*)(LA0 + aoff[mi]);
    #pragma unroll
    for (int ni = 0; ni < 4; ++ni) bv[ni] = *(const bf16x8*)(LB0 + boff[ni]);
    if (s) {
      gload16(pA,  dA + nb * AHALFR + da);
      gload16(pB0, dB + nb * BHALFR + db0); gload16(pB1, dB + nb * BHALFR + db1);
    }
    __builtin_amdgcn_s_setprio(1);
    #pragma unroll
    for (int mi = 0; mi < 4; ++mi)
      #pragma unroll
      for (int ni = 0; ni < 4; ++ni)
        acc[mi][ni] = __builtin_amdgcn_mfma_f32_16x16x32_bf16(av[mi], bv[ni], acc[mi][ni], 0, 0, 0);
    __builtin_amdgcn_s_setprio(0);
    if (s) { WAITVM3; } else { WAITVM0; }
    SBAR;

    #pragma unroll
    for (int mi = 0; mi < 4; ++mi) av[mi] = *(const bf16x8*)(LA1 + aoff[mi]);
    #pragma unroll
    for (int ni = 0; ni < 4; ++ni) bv[ni] = *(const bf16x8*)(LB1 + boff[ni]);
    if (s) {
      gload16(pA + 32,  dA + nb * AHALFR + AHALFR + da);
      gload16(pB0 + 32, dB + nb * BHALFR + BHALFR + db0);
      gload16(pB1 + 32, dB + nb * BHALFR + BHALFR + db1);
      pA += BK; pB0 += BK; pB1 += BK;
    }
    __builtin_amdgcn_s_setprio(1);
    #pragma unroll
    for (int mi = 0; mi < 4; ++mi)
      #pragma unroll
      for (int ni = 0; ni < 4; ++ni)
        acc[mi][ni] = __builtin_amdgcn_mfma_f32_16x16x32_bf16(av[mi], bv[ni], acc[mi][ni], 0, 0, 0);
    __builtin_amdgcn_s_setprio(0);
    if (s) { WAITVM3; }
    SBAR;
  }
}

// ---------------- fp32 -> bf16 convert (vectorized) ----------------
__global__ __launch_bounds__(256) void k_cvt(const float* __restrict__ in,
                                             u16* __restrict__ out, int n) {
  int i = (blockIdx.x * 256 + threadIdx.x) * 4;
  if (i >= n) return;
  float4 v = *(const float4*)(in + i);
  ushort4 o;
  o.x = f2bf(v.x); o.y = f2bf(v.y); o.z = f2bf(v.z); o.w = f2bf(v.w);
  *(ushort4*)(out + i) = o;
}

// 3 weight matrices in one launch (blockIdx.y selects)
__global__ __launch_bounds__(256) void k_cvtw(const float* __restrict__ w0,
                                              const float* __restrict__ w1,
                                              const float* __restrict__ w2,
                                              u16* __restrict__ out) {
  const float* in = (blockIdx.y == 0) ? w0 : (blockIdx.y == 1) ? w1 : w2;
  u16* o = out + (size_t)blockIdx.y * EMBED * EMBED;
  int i = (blockIdx.x * 256 + threadIdx.x) * 4;
  float4 v = *(const float4*)(in + i);
  ushort4 r;
  r.x = f2bf(v.x); r.y = f2bf(v.y); r.z = f2bf(v.z); r.w = f2bf(v.w);
  *(ushort4*)(o + i) = r;
}

// ---------------- QKV projection: C = X * W^T + b ----------------
__global__ __launch_bounds__(512, 2) void k_qkv(
    const u16* __restrict__ Xb, const u16* __restrict__ Wb,
    const float* __restrict__ bq, const float* __restrict__ bk, const float* __restrict__ bv,
    u16* __restrict__ Q, u16* __restrict__ Ks, u16* __restrict__ V)
{
  __shared__ u16 lds[8 * HALF2];
  const int m0 = blockIdx.x * BM2;
  const int n0 = blockIdx.y * BN2;
  const int z  = blockIdx.z;
  const u16*   W    = Wb + (size_t)z * EMBED * EMBED;
  const float* bias = (z == 0) ? bq : (z == 1) ? bk : bv;
  u16* out          = (z == 0) ? Q  : (z == 1) ? Ks : V;
  const float scale = (z == 1) ? KSCALE : 1.0f;

  f32x4 acc[8][4];
  const f32x4 zz = {0.f,0.f,0.f,0.f};
  #pragma unroll
  for (int i = 0; i < 8; ++i) for (int j = 0; j < 4; ++j) acc[i][j] = zz;
  gemm256(Xb + (size_t)m0 * EMBED, EMBED, W + (size_t)n0 * EMBED, EMBED,
          EMBED / BK, lds, acc);

  const int lane = threadIdx.x & 63, wid = threadIdx.x >> 6;
  const int wm = (wid >> 2) * 128, wn = (wid & 3) * 64;
  const int lrow = lane & 15, hi = lane >> 4;
  #pragma unroll
  for (int mi = 0; mi < 8; ++mi)
    #pragma unroll
    for (int ni = 0; ni < 4; ++ni)
      #pragma unroll
      for (int rr = 0; rr < 4; ++rr) {
        int gm = m0 + wm + mi * 16 + hi * 4 + rr;
        int gn = n0 + wn + ni * 16 + lrow;
        out[(size_t)gm * EMBED + gn] = f2bf((acc[mi][ni][rr] + bias[gn]) * scale);
      }
}

// -- S = Q*K^T, P = exp2(S) masked, D[j] += colsum; XCD-pinned hybrid grid --
__global__ __launch_bounds__(512, 2) void k_spd(
    const u16* __restrict__ Q, const u16* __restrict__ Ks,
    u16* __restrict__ P, float* __restrict__ D)
{
  __shared__ u16 lds[BM2 * PLD];
  const int sblk = blockIdx.x;

  if (sblk < 256) {
    const int xcd = sblk & 7;
    const int q   = sblk >> 3;            // 0..31
    int it = 0;
    while (q >= ((it + 1) * (it + 2)) / 2) ++it;
    const int jt = q - (it * (it + 1)) / 2;
    const int b  = (xcd - it) & 7;
    const int i0 = it * BM2;
    const int j0 = jt * BN2;

    const u16* A = Q  + (size_t)b * WINDOW * EMBED + (size_t)i0 * EMBED;
    const u16* B = Ks + (size_t)b * WINDOW * EMBED + (size_t)j0 * EMBED;
    f32x4 acc[8][4];
    const f32x4 zz = {0.f,0.f,0.f,0.f};
    #pragma unroll
    for (int i = 0; i < 8; ++i) for (int j = 0; j < 4; ++j) acc[i][j] = zz;
    gemm256(A, EMBED, B, EMBED, EMBED / BK, lds, acc);

    u16* Pb   = P + (size_t)b * WINDOW * WINDOW;
    float* Db = D + (size_t)b * WINDOW;
    const int tid  = threadIdx.x;
    const int lane = tid & 63, wid = tid >> 6;
    const int wm = (wid >> 2) * 128, wn = (wid & 3) * 64;
    const int lrow = lane & 15, hi = lane >> 4;

    #pragma unroll
    for (int ni = 0; ni < 4; ++ni) {
      int lj = wn + ni * 16 + lrow;
      float csum = 0.f;
      #pragma unroll
      for (int mi = 0; mi < 8; ++mi)
        #pragma unroll
        for (int rr = 0; rr < 4; ++rr) {
          int li = wm + mi * 16 + hi * 4 + rr;
          float p = ((i0 + li) >= (j0 + lj)) ? exp2f(acc[mi][ni][rr]) : 0.0f;
          lds[li * PLD + lj] = f2bf(p);
          csum += p;
        }
      csum += __shfl_xor(csum, 16, 64);
      csum += __shfl_xor(csum, 32, 64);
      if (hi == 0) atomicAdd(&Db[j0 + lj], csum);
    }
    __syncthreads();

    #pragma unroll
    for (int it2 = 0; it2 < 16; ++it2) {
      int f   = it2 * 512 + tid;
      int row = f >> 5;
      int c   = f & 31;
      bf16x8 v = *(const bf16x8*)(lds + row * PLD + c * 8);
      *(bf16x8*)(Pb + (size_t)(i0 + row) * WINDOW + j0 + c * 8) = v;
    }
  } else {
    const int ih   = sblk - 256;          // 0..63
    const int xcd  = ih & 7;
    const int h    = ih >> 3;             // 0..7
    const int jt   = 4 + (h >> 1);
    const int half = h & 1;
    const int it   = 7;
    const int b    = (xcd - it) & 7;
    const int i0   = it * BM2 + half * 128;
    const int j0   = jt * BN2;

    const u16* A = Q  + (size_t)b * WINDOW * EMBED + (size_t)i0 * EMBED;
    const u16* B = Ks + (size_t)b * WINDOW * EMBED + (size_t)j0 * EMBED;
    f32x4 acc[4][4];
    const f32x4 zz = {0.f,0.f,0.f,0.f};
    #pragma unroll
    for (int i = 0; i < 4; ++i) for (int j = 0; j < 4; ++j) acc[i][j] = zz;
    gemm_rect(A, EMBED, B, EMBED, EMBED / BK, lds, acc);

    u16* Pb   = P + (size_t)b * WINDOW * WINDOW;
    float* Db = D + (size_t)b * WINDOW;
    const int lane = threadIdx.x & 63, wid = threadIdx.x >> 6;
    const int wm = (wid >> 2) * 64, wn = (wid & 3) * 64;
    const int lrow = lane & 15, hi = lane >> 4;
    #pragma unroll
    for (int ni = 0; ni < 4; ++ni) {
      int gj = j0 + wn + ni * 16 + lrow;
      float csum = 0.f;
      #pragma unroll
      for (int mi = 0; mi < 4; ++mi)
        #pragma unroll
        for (int rr = 0; rr < 4; ++rr) {
          int gi = i0 + wm + mi * 16 + hi * 4 + rr;
          float p = (gi >= gj) ? exp2f(acc[mi][ni][rr]) : 0.0f;
          Pb[(size_t)gi * WINDOW + gj] = f2bf(p);
          csum += p;
        }
      csum += __shfl_xor(csum, 16, 64);
      csum += __shfl_xor(csum, 32, 64);
      if (hi == 0) atomicAdd(&Db[gj], csum);
    }
  }
}

// ---------------- Vdt[e][j] = V[j][e] / D[j]  (transpose + scale) ----------------
__global__ __launch_bounds__(256) void k_vdt(
    const u16* __restrict__ V, const float* __restrict__ D, u16* __restrict__ Vdt)
{
  __shared__ u16 tile[64][68];
  const int j0 = blockIdx.x * 64, e0 = blockIdx.y * 64, b = blockIdx.z;
  const u16* Vb = V   + (size_t)b * WINDOW * EMBED;
  u16* Tb       = Vdt + (size_t)b * EMBED * WINDOW;
  const float* Db = D + (size_t)b * WINDOW;
  const int t = threadIdx.x;
  const int rr = t >> 4;
  const int cc = (t & 15) * 4;
  #pragma unroll
  for (int p = 0; p < 4; ++p) {
    int r = p * 16 + rr;
    *(uint2*)&tile[r][cc] = *(const uint2*)(Vb + (size_t)(j0 + r) * EMBED + e0 + cc);
  }
  __syncthreads();
  #pragma unroll
  for (int p = 0; p < 4; ++p) {
    int er = p * 16 + rr;
    ushort4 o;
    o.x = f2bf(bf2f(tile[cc + 0][er]) / Db[j0 + cc + 0]);
    o.y = f2bf(bf2f(tile[cc + 1][er]) / Db[j0 + cc + 1]);
    o.z = f2bf(bf2f(tile[cc + 2][er]) / Db[j0 + cc + 2]);
    o.w = f2bf(bf2f(tile[cc + 3][er]) / Db[j0 + cc + 3]);
    *(ushort4*)(Tb + (size_t)(e0 + er) * WINDOW + j0 + cc) = o;
  }
}

// ---- O = P * Vdt^T, XCD-pinned balanced grid: it<=3 full jobs, it>=4 K-split
// halves (efficient 256^2 core, fp32 atomicAdd partials; O rows >=1024 pre-zeroed).
// 48 jobs/XCD, longest-first: makespan ~22 K-tiles vs 32 before. ----
__global__ __launch_bounds__(512, 2) void k_out(
    const u16* __restrict__ P, const u16* __restrict__ Vdt, float* __restrict__ O)
{
  __shared__ u16 lds[8 * HALF2];
  const int s   = blockIdx.x;
  const int xcd = s & 7;
  const int q   = s >> 3;            // 0..47, descending cost order
  int it, et, kh = -1;
  if      (q <  8) { it = 7; kh = (q >> 2) & 1;        et = q & 3;        }
  else if (q < 12) { it = 3;                           et = q - 8;        }
  else if (q < 20) { it = 6; kh = ((q - 12) >> 2) & 1; et = (q - 12) & 3; }
  else if (q < 28) { it = 5; kh = ((q - 20) >> 2) & 1; et = (q - 20) & 3; }
  else if (q < 32) { it = 2;                           et = q - 28;       }
  else if (q < 40) { it = 4; kh = ((q - 32) >> 2) & 1; et = (q - 32) & 3; }
  else if (q < 44) { it = 1;                           et = q - 40;       }
  else             { it = 0;                           et = q - 44;       }

  const int b  = (xcd - it) & 7;
  const int i0 = it * BM2;
  const int e0 = et * BN2;
  const int ntfull = 4 * (it + 1);
  const int nt     = (kh < 0) ? ntfull : ntfull / 2;
  const int kstart = (kh <= 0) ? 0 : nt;             // K-tile offset

  const u16* A = P   + (size_t)b * WINDOW * WINDOW + (size_t)i0 * WINDOW + (size_t)kstart * BK;
  const u16* B = Vdt + (size_t)b * EMBED * WINDOW  + (size_t)e0 * WINDOW + (size_t)kstart * BK;
  f32x4 acc[8][4];
  const f32x4 zz = {0.f,0.f,0.f,0.f};
  #pragma unroll
  for (int i = 0; i < 8; ++i) for (int j = 0; j < 4; ++j) acc[i][j] = zz;
  gemm256(A, WINDOW, B, WINDOW, nt, lds, acc);

  float* Ob = O + (size_t)b * WINDOW * EMBED;
  const int lane = threadIdx.x & 63, wid = threadIdx.x >> 6;
  const int wm = (wid >> 2) * 128, wn = (wid & 3) * 64;
  const int lrow = lane & 15, hi = lane >> 4;
  if (kh < 0) {
    #pragma unroll
    for (int mi = 0; mi < 8; ++mi)
      #pragma unroll
      for (int ni = 0; ni < 4; ++ni)
        #pragma unroll
        for (int rr = 0; rr < 4; ++rr) {
          int gi = i0 + wm + mi * 16 + hi * 4 + rr;
          int ge = e0 + wn + ni * 16 + lrow;
          Ob[(size_t)gi * EMBED + ge] = acc[mi][ni][rr];
        }
  } else {
    #pragma unroll
    for (int mi = 0; mi < 8; ++mi)
      #pragma unroll
      for (int ni = 0; ni < 4; ++ni)
        #pragma unroll
        for (int rr = 0; rr < 4; ++rr) {
          int gi = i0 + wm + mi * 16 + hi * 4 + rr;
          int ge = e0 + wn + ni * 16 + lrow;
          atomicAdd(&Ob[(size_t)gi * EMBED + ge], acc[mi][ni][rr]);
        }
  }
}

extern "C" void kernel_launch(void* const* d_in, const int* in_sizes, int n_in,
                              void* d_out, int out_size, void* d_ws, size_t ws_size,
                              hipStream_t stream) {
  const float* X  = (const float*)d_in[0];
  const float* Wq = (const float*)d_in[1];
  const float* bq = (const float*)d_in[2];
  const float* Wk = (const float*)d_in[3];
  const float* bk = (const float*)d_in[4];
  const float* Wv = (const float*)d_in[5];
  const float* bv = (const float*)d_in[6];
  float* O = (float*)d_out;

  char* ws = (char*)d_ws;
  size_t off = 0;
  auto alloc = [&](size_t bytes) -> void* {
    void* p = ws + off; off += (bytes + 255) & ~(size_t)255; return p;
  };
  u16*  Xb  = (u16*)alloc((size_t)MTOT * EMBED * 2);
  u16*  Wb  = (u16*)alloc((size_t)3 * EMBED * EMBED * 2);
  u16*  Qb  = (u16*)alloc((size_t)MTOT * EMBED * 2);
  u16*  Kb  = (u16*)alloc((size_t)MTOT * EMBED * 2);          // pre-scaled by log2e/32
  u16*  Vb  = (u16*)alloc((size_t)MTOT * EMBED * 2);
  u16*  Vdt = (u16*)alloc((size_t)BATCH * EMBED * WINDOW * 2);
  u16*  P   = (u16*)alloc((size_t)BATCH * WINDOW * WINDOW * 2);
  float* D  = (float*)alloc((size_t)MTOT * 4);
  (void)ws_size; (void)in_sizes; (void)n_in; (void)out_size;

  // 0) fp32 -> bf16 converts (X; then all 3 W's in one launch)
  k_cvt<<<dim3((MTOT * EMBED / 4 + 255) / 256), 256, 0, stream>>>(X, Xb, MTOT * EMBED);
  k_cvtw<<<dim3(EMBED * EMBED / 4 / 256, 3), 256, 0, stream>>>(Wq, Wk, Wv, Wb);

  // 1) Q/K/V projections (768 blocks = 3 dispatch rounds)
  k_qkv<<<dim3(MTOT / BM2, EMBED / BN2, 3), 512, 0, stream>>>(Xb, Wb, bq, bk, bv, Qb, Kb, Vb);

  // 2) P = exp(QK^T/sqrt(E)) masked; D[j] = column sums (hybrid 320-job grid)
  (void)hipMemsetAsync(D, 0, (size_t)MTOT * 4, stream);
  k_spd<<<dim3(320), 512, 0, stream>>>(Qb, Kb, P, D);

  // 3) Vdt[e][j] = V[j][e] / D[j]; zero O rows >=1024 per batch (K-split targets)
  k_vdt<<<dim3(WINDOW / 64, EMBED / 64, BATCH), 256, 0, stream>>>(Vb, D, Vdt);
  for (int b = 0; b < BATCH; ++b)
    (void)hipMemsetAsync(O + ((size_t)b * WINDOW + 1024) * EMBED, 0,
                         (size_t)1024 * EMBED * 4, stream);

  // 4) O = P * Vdt^T (384 balanced XCD-pinned jobs: fulls + K-split halves)
  k_out<<<dim3(384), 512, 0, stream>>>(P, Vdt, O);
}

// Round 19
// 264.271 us; speedup vs baseline: 1.1855x; 1.1855x over previous
//
#include <hip/hip_runtime.h>
#include <stdint.h>

#define WINDOW 2048
#define EMBED  1024
#define BATCH  8
#define MTOT   (BATCH*WINDOW)   // 16384 rows total

typedef unsigned short u16;
typedef __bf16 bf16x8 __attribute__((ext_vector_type(8)));
typedef float  f32x4  __attribute__((ext_vector_type(4)));

#define BK 64
#define KSCALE 0.04508422717564447f   /* log2(e)/32 folded into stored K */

// ---- 256x256 tile, 8 waves (2M x 4N -> 128x64/wave), kk-split halves ----
#define BM2 256
#define BN2 256
#define HALF2 8192    // kk-half: 256r x 32c (16 KiB); 8 halves = 128 KiB
#define PLD  260      // padded LDS row (u16) for the P-bounce epilogue

// ---- 128x256 rect core (tail half-jobs): 8 waves 2Mx4N -> 64x64/wave ----
#define AHALFR 4096   // A kk-half: 128r x 32c (8 KiB)
#define BHALFR 8192   // B kk-half: 256r x 32c (16 KiB)  -> total 96 KiB

#define WAITVM4 asm volatile("s_waitcnt vmcnt(4)" ::: "memory")
#define WAITVM3 asm volatile("s_waitcnt vmcnt(3)" ::: "memory")
#define WAITVM0 asm volatile("s_waitcnt vmcnt(0)" ::: "memory")
#define SBAR    __builtin_amdgcn_s_barrier()

__device__ __forceinline__ u16 f2bf(float f) {
  union { float f; unsigned u; } a; a.f = f;
  unsigned r = a.u + 0x7FFF + ((a.u >> 16) & 1);   // RNE
  return (u16)(r >> 16);
}
__device__ __forceinline__ float bf2f(u16 u) {
  union { unsigned u; float f; } a; a.u = ((unsigned)u) << 16;
  return a.f;
}

__device__ __forceinline__ void gload16(const u16* g, u16* l) {
  __builtin_amdgcn_global_load_lds(
      (const __attribute__((address_space(1))) unsigned int*)g,
      (__attribute__((address_space(3))) unsigned int*)l, 16, 0, 0);
}

// Swizzle (rule #21): LDS dest LINEAR slot f = r*4 + c; global SOURCE chunk is
// c ^ ((r>>1)&3) (involution) so a read at slot hi^((r>>1)&3) sees logical
// chunk hi.  ds_read_b128 lands 2-way bank-aliased only (free, m136).

// ============ 256x256 core: acc[8][4], 2 phases/K-tile (32 MFMA each) ============
__device__ __forceinline__ void gemm256(
    const u16* __restrict__ A, int lda,
    const u16* __restrict__ B, int ldb,
    int nt, u16* lds, f32x4 acc[8][4])
{
  const int tid  = threadIdx.x;
  const int lane = tid & 63;
  const int wid  = tid >> 6;
  const int wm   = (wid >> 2) * 128;
  const int wn   = (wid & 3) * 64;
  const int lrow = lane & 15;
  const int hi   = lane >> 4;
  u16* dA = lds;
  u16* dB = lds + 4 * HALF2;

  int aoff[8], boff[4];
  #pragma unroll
  for (int mi = 0; mi < 8; ++mi) {
    int r = wm + mi * 16 + lrow;
    aoff[mi] = r * 32 + ((hi ^ ((r >> 1) & 3)) << 3);
  }
  #pragma unroll
  for (int ni = 0; ni < 4; ++ni) {
    int r = wn + ni * 16 + lrow;
    boff[ni] = r * 32 + ((hi ^ ((r >> 1) & 3)) << 3);
  }

  const int f0 = tid, f1 = 512 + tid;
  const int r0 = f0 >> 2, r1 = f1 >> 2;
  const int c0 = (((f0 & 3) ^ ((r0 >> 1) & 3)) << 3);
  const int c1 = (((f1 & 3) ^ ((r1 >> 1) & 3)) << 3);
  const u16* pA0 = A + (size_t)r0 * lda + c0;
  const u16* pA1 = A + (size_t)r1 * lda + c1;
  const u16* pB0 = B + (size_t)r0 * ldb + c0;
  const u16* pB1 = B + (size_t)r1 * ldb + c1;
  const int d0 = f0 * 8, d1 = f1 * 8;

  gload16(pA0,      dA + d0);         gload16(pA1,      dA + d1);
  gload16(pB0,      dB + d0);         gload16(pB1,      dB + d1);
  gload16(pA0 + 32, dA + HALF2 + d0); gload16(pA1 + 32, dA + HALF2 + d1);
  gload16(pB0 + 32, dB + HALF2 + d0); gload16(pB1 + 32, dB + HALF2 + d1);
  pA0 += BK; pA1 += BK; pB0 += BK; pB1 += BK;
  WAITVM4;
  SBAR;

  for (int t = 0; t < nt; ++t) {
    const int cb = (t & 1) * 2;
    const int nb = ((t + 1) & 1) * 2;
    u16* LA0 = dA + cb * HALF2;  u16* LA1 = LA0 + HALF2;
    u16* LB0 = dB + cb * HALF2;  u16* LB1 = LB0 + HALF2;
    const bool s = (t + 1) < nt;
    bf16x8 av[8], bv[4];

    #pragma unroll
    for (int mi = 0; mi < 8; ++mi) av[mi] = *(const bf16x8*)(LA0 + aoff[mi]);
    #pragma unroll
    for (int ni = 0; ni < 4; ++ni) bv[ni] = *(const bf16x8*)(LB0 + boff[ni]);
    if (s) {
      gload16(pA0, dA + nb * HALF2 + d0); gload16(pA1, dA + nb * HALF2 + d1);
      gload16(pB0, dB + nb * HALF2 + d0); gload16(pB1, dB + nb * HALF2 + d1);
    }
    __builtin_amdgcn_s_setprio(1);
    #pragma unroll
    for (int mi = 0; mi < 8; ++mi)
      #pragma unroll
      for (int ni = 0; ni < 4; ++ni)
        acc[mi][ni] = __builtin_amdgcn_mfma_f32_16x16x32_bf16(av[mi], bv[ni], acc[mi][ni], 0, 0, 0);
    __builtin_amdgcn_s_setprio(0);
    if (s) { WAITVM4; } else { WAITVM0; }
    SBAR;

    #pragma unroll
    for (int mi = 0; mi < 8; ++mi) av[mi] = *(const bf16x8*)(LA1 + aoff[mi]);
    #pragma unroll
    for (int ni = 0; ni < 4; ++ni) bv[ni] = *(const bf16x8*)(LB1 + boff[ni]);
    if (s) {
      gload16(pA0 + 32, dA + nb * HALF2 + HALF2 + d0); gload16(pA1 + 32, dA + nb * HALF2 + HALF2 + d1);
      gload16(pB0 + 32, dB + nb * HALF2 + HALF2 + d0); gload16(pB1 + 32, dB + nb * HALF2 + HALF2 + d1);
      pA0 += BK; pA1 += BK; pB0 += BK; pB1 += BK;
    }
    __builtin_amdgcn_s_setprio(1);
    #pragma unroll
    for (int mi = 0; mi < 8; ++mi)
      #pragma unroll
      for (int ni = 0; ni < 4; ++ni)
        acc[mi][ni] = __builtin_amdgcn_mfma_f32_16x16x32_bf16(av[mi], bv[ni], acc[mi][ni], 0, 0, 0);
    __builtin_amdgcn_s_setprio(0);
    if (s) { WAITVM4; }
    SBAR;
  }
}

// ===== 128x256 rect core (verified R5/R17): acc[4][4], 2 phases/K-tile =====
__device__ __forceinline__ void gemm_rect(
    const u16* __restrict__ A, int lda,
    const u16* __restrict__ B, int ldb,
    int nt, u16* lds, f32x4 acc[4][4])
{
  const int tid  = threadIdx.x;
  const int lane = tid & 63;
  const int wid  = tid >> 6;
  const int wm   = (wid >> 2) * 64;   // 0/64
  const int wn   = (wid & 3) * 64;    // 0..192
  const int lrow = lane & 15;
  const int hi   = lane >> 4;
  u16* dA = lds;
  u16* dB = lds + 4 * AHALFR;

  int aoff[4], boff[4];
  #pragma unroll
  for (int mi = 0; mi < 4; ++mi) {
    int r = wm + mi * 16 + lrow;
    aoff[mi] = r * 32 + ((hi ^ ((r >> 1) & 3)) << 3);
  }
  #pragma unroll
  for (int ni = 0; ni < 4; ++ni) {
    int r = wn + ni * 16 + lrow;
    boff[ni] = r * 32 + ((hi ^ ((r >> 1) & 3)) << 3);
  }

  const int fa = tid;
  const int fb0 = tid, fb1 = 512 + tid;
  const int ra = fa >> 2, rb0 = fb0 >> 2, rb1 = fb1 >> 2;
  const int ca  = (((fa  & 3) ^ ((ra  >> 1) & 3)) << 3);
  const int cb0 = (((fb0 & 3) ^ ((rb0 >> 1) & 3)) << 3);
  const int cb1 = (((fb1 & 3) ^ ((rb1 >> 1) & 3)) << 3);
  const u16* pA  = A + (size_t)ra  * lda + ca;
  const u16* pB0 = B + (size_t)rb0 * ldb + cb0;
  const u16* pB1 = B + (size_t)rb1 * ldb + cb1;
  const int da = fa * 8, db0 = fb0 * 8, db1 = fb1 * 8;

  gload16(pA,       dA + da);
  gload16(pB0,      dB + db0);          gload16(pB1,      dB + db1);
  gload16(pA + 32,  dA + AHALFR + da);
  gload16(pB0 + 32, dB + BHALFR + db0); gload16(pB1 + 32, dB + BHALFR + db1);
  pA += BK; pB0 += BK; pB1 += BK;
  WAITVM3;
  SBAR;

  for (int t = 0; t < nt; ++t) {
    const int cb = (t & 1) * 2;
    const int nb = ((t + 1) & 1) * 2;
    u16* LA0 = dA + cb * AHALFR;  u16* LA1 = LA0 + AHALFR;
    u16* LB0 = dB + cb * BHALFR;  u16* LB1 = LB0 + BHALFR;
    const bool s = (t + 1) < nt;
    bf16x8 av[4], bv[4];

    #pragma unroll
    for (int mi = 0; mi < 4; ++mi) av[mi] = *(const bf16x8*)(LA0 + aoff[mi]);
    #pragma unroll
    for (int ni = 0; ni < 4; ++ni) bv[ni] = *(const bf16x8*)(LB0 + boff[ni]);
    if (s) {
      gload16(pA,  dA + nb * AHALFR + da);
      gload16(pB0, dB + nb * BHALFR + db0); gload16(pB1, dB + nb * BHALFR + db1);
    }
    __builtin_amdgcn_s_setprio(1);
    #pragma unroll
    for (int mi = 0; mi < 4; ++mi)
      #pragma unroll
      for (int ni = 0; ni < 4; ++ni)
        acc[mi][ni] = __builtin_amdgcn_mfma_f32_16x16x32_bf16(av[mi], bv[ni], acc[mi][ni], 0, 0, 0);
    __builtin_amdgcn_s_setprio(0);
    if (s) { WAITVM3; } else { WAITVM0; }
    SBAR;

    #pragma unroll
    for (int mi = 0; mi < 4; ++mi) av[mi] = *(const bf16x8*)(LA1 + aoff[mi]);
    #pragma unroll
    for (int ni = 0; ni < 4; ++ni) bv[ni] = *(const bf16x8*)(LB1 + boff[ni]);
    if (s) {
      gload16(pA + 32,  dA + nb * AHALFR + AHALFR + da);
      gload16(pB0 + 32, dB + nb * BHALFR + BHALFR + db0);
      gload16(pB1 + 32, dB + nb * BHALFR + BHALFR + db1);
      pA += BK; pB0 += BK; pB1 += BK;
    }
    __builtin_amdgcn_s_setprio(1);
    #pragma unroll
    for (int mi = 0; mi < 4; ++mi)
      #pragma unroll
      for (int ni = 0; ni < 4; ++ni)
        acc[mi][ni] = __builtin_amdgcn_mfma_f32_16x16x32_bf16(av[mi], bv[ni], acc[mi][ni], 0, 0, 0);
    __builtin_amdgcn_s_setprio(0);
    if (s) { WAITVM3; }
    SBAR;
  }
}

// ---------------- fp32 -> bf16 convert (vectorized) ----------------
__global__ __launch_bounds__(256) void k_cvt(const float* __restrict__ in,
                                             u16* __restrict__ out, int n) {
  int i = (blockIdx.x * 256 + threadIdx.x) * 4;
  if (i >= n) return;
  float4 v = *(const float4*)(in + i);
  ushort4 o;
  o.x = f2bf(v.x); o.y = f2bf(v.y); o.z = f2bf(v.z); o.w = f2bf(v.w);
  *(ushort4*)(out + i) = o;
}

// 3 weight matrices in one launch (blockIdx.y selects)
__global__ __launch_bounds__(256) void k_cvtw(const float* __restrict__ w0,
                                              const float* __restrict__ w1,
                                              const float* __restrict__ w2,
                                              u16* __restrict__ out) {
  const float* in = (blockIdx.y == 0) ? w0 : (blockIdx.y == 1) ? w1 : w2;
  u16* o = out + (size_t)blockIdx.y * EMBED * EMBED;
  int i = (blockIdx.x * 256 + threadIdx.x) * 4;
  float4 v = *(const float4*)(in + i);
  ushort4 r;
  r.x = f2bf(v.x); r.y = f2bf(v.y); r.z = f2bf(v.z); r.w = f2bf(v.w);
  *(ushort4*)(o + i) = r;
}

// ---------------- QKV projection: C = X * W^T + b ----------------
__global__ __launch_bounds__(512, 2) void k_qkv(
    const u16* __restrict__ Xb, const u16* __restrict__ Wb,
    const float* __restrict__ bq, const float* __restrict__ bk, const float* __restrict__ bv,
    u16* __restrict__ Q, u16* __restrict__ Ks, u16* __restrict__ V)
{
  __shared__ u16 lds[8 * HALF2];
  const int m0 = blockIdx.x * BM2;
  const int n0 = blockIdx.y * BN2;
  const int z  = blockIdx.z;
  const u16*   W    = Wb + (size_t)z * EMBED * EMBED;
  const float* bias = (z == 0) ? bq : (z == 1) ? bk : bv;
  u16* out          = (z == 0) ? Q  : (z == 1) ? Ks : V;
  const float scale = (z == 1) ? KSCALE : 1.0f;

  f32x4 acc[8][4];
  const f32x4 zz = {0.f,0.f,0.f,0.f};
  #pragma unroll
  for (int i = 0; i < 8; ++i) for (int j = 0; j < 4; ++j) acc[i][j] = zz;
  gemm256(Xb + (size_t)m0 * EMBED, EMBED, W + (size_t)n0 * EMBED, EMBED,
          EMBED / BK, lds, acc);

  const int lane = threadIdx.x & 63, wid = threadIdx.x >> 6;
  const int wm = (wid >> 2) * 128, wn = (wid & 3) * 64;
  const int lrow = lane & 15, hi = lane >> 4;
  #pragma unroll
  for (int mi = 0; mi < 8; ++mi)
    #pragma unroll
    for (int ni = 0; ni < 4; ++ni)
      #pragma unroll
      for (int rr = 0; rr < 4; ++rr) {
        int gm = m0 + wm + mi * 16 + hi * 4 + rr;
        int gn = n0 + wn + ni * 16 + lrow;
        out[(size_t)gm * EMBED + gn] = f2bf((acc[mi][ni][rr] + bias[gn]) * scale);
      }
}

// -- S = Q*K^T, P = exp2(S) masked, D[j] += colsum; XCD-pinned hybrid grid --
__global__ __launch_bounds__(512, 2) void k_spd(
    const u16* __restrict__ Q, const u16* __restrict__ Ks,
    u16* __restrict__ P, float* __restrict__ D)
{
  __shared__ u16 lds[BM2 * PLD];
  const int sblk = blockIdx.x;

  if (sblk < 256) {
    const int xcd = sblk & 7;
    const int q   = sblk >> 3;            // 0..31
    int it = 0;
    while (q >= ((it + 1) * (it + 2)) / 2) ++it;
    const int jt = q - (it * (it + 1)) / 2;
    const int b  = (xcd - it) & 7;
    const int i0 = it * BM2;
    const int j0 = jt * BN2;

    const u16* A = Q  + (size_t)b * WINDOW * EMBED + (size_t)i0 * EMBED;
    const u16* B = Ks + (size_t)b * WINDOW * EMBED + (size_t)j0 * EMBED;
    f32x4 acc[8][4];
    const f32x4 zz = {0.f,0.f,0.f,0.f};
    #pragma unroll
    for (int i = 0; i < 8; ++i) for (int j = 0; j < 4; ++j) acc[i][j] = zz;
    gemm256(A, EMBED, B, EMBED, EMBED / BK, lds, acc);

    u16* Pb   = P + (size_t)b * WINDOW * WINDOW;
    float* Db = D + (size_t)b * WINDOW;
    const int tid  = threadIdx.x;
    const int lane = tid & 63, wid = tid >> 6;
    const int wm = (wid >> 2) * 128, wn = (wid & 3) * 64;
    const int lrow = lane & 15, hi = lane >> 4;

    #pragma unroll
    for (int ni = 0; ni < 4; ++ni) {
      int lj = wn + ni * 16 + lrow;
      float csum = 0.f;
      #pragma unroll
      for (int mi = 0; mi < 8; ++mi)
        #pragma unroll
        for (int rr = 0; rr < 4; ++rr) {
          int li = wm + mi * 16 + hi * 4 + rr;
          float p = ((i0 + li) >= (j0 + lj)) ? exp2f(acc[mi][ni][rr]) : 0.0f;
          lds[li * PLD + lj] = f2bf(p);
          csum += p;
        }
      csum += __shfl_xor(csum, 16, 64);
      csum += __shfl_xor(csum, 32, 64);
      if (hi == 0) atomicAdd(&Db[j0 + lj], csum);
    }
    __syncthreads();

    #pragma unroll
    for (int it2 = 0; it2 < 16; ++it2) {
      int f   = it2 * 512 + tid;
      int row = f >> 5;
      int c   = f & 31;
      bf16x8 v = *(const bf16x8*)(lds + row * PLD + c * 8);
      *(bf16x8*)(Pb + (size_t)(i0 + row) * WINDOW + j0 + c * 8) = v;
    }
  } else {
    const int ih   = sblk - 256;          // 0..63
    const int xcd  = ih & 7;
    const int h    = ih >> 3;             // 0..7
    const int jt   = 4 + (h >> 1);
    const int half = h & 1;
    const int it   = 7;
    const int b    = (xcd - it) & 7;
    const int i0   = it * BM2 + half * 128;
    const int j0   = jt * BN2;

    const u16* A = Q  + (size_t)b * WINDOW * EMBED + (size_t)i0 * EMBED;
    const u16* B = Ks + (size_t)b * WINDOW * EMBED + (size_t)j0 * EMBED;
    f32x4 acc[4][4];
    const f32x4 zz = {0.f,0.f,0.f,0.f};
    #pragma unroll
    for (int i = 0; i < 4; ++i) for (int j = 0; j < 4; ++j) acc[i][j] = zz;
    gemm_rect(A, EMBED, B, EMBED, EMBED / BK, lds, acc);

    u16* Pb   = P + (size_t)b * WINDOW * WINDOW;
    float* Db = D + (size_t)b * WINDOW;
    const int lane = threadIdx.x & 63, wid = threadIdx.x >> 6;
    const int wm = (wid >> 2) * 64, wn = (wid & 3) * 64;
    const int lrow = lane & 15, hi = lane >> 4;
    #pragma unroll
    for (int ni = 0; ni < 4; ++ni) {
      int gj = j0 + wn + ni * 16 + lrow;
      float csum = 0.f;
      #pragma unroll
      for (int mi = 0; mi < 4; ++mi)
        #pragma unroll
        for (int rr = 0; rr < 4; ++rr) {
          int gi = i0 + wm + mi * 16 + hi * 4 + rr;
          float p = (gi >= gj) ? exp2f(acc[mi][ni][rr]) : 0.0f;
          Pb[(size_t)gi * WINDOW + gj] = f2bf(p);
          csum += p;
        }
      csum += __shfl_xor(csum, 16, 64);
      csum += __shfl_xor(csum, 32, 64);
      if (hi == 0) atomicAdd(&Db[gj], csum);
    }
  }
}

// ---------------- Vdt[e][j] = V[j][e] / D[j]  (transpose + scale) ----------------
__global__ __launch_bounds__(256) void k_vdt(
    const u16* __restrict__ V, const float* __restrict__ D, u16* __restrict__ Vdt)
{
  __shared__ u16 tile[64][68];
  const int j0 = blockIdx.x * 64, e0 = blockIdx.y * 64, b = blockIdx.z;
  const u16* Vb = V   + (size_t)b * WINDOW * EMBED;
  u16* Tb       = Vdt + (size_t)b * EMBED * WINDOW;
  const float* Db = D + (size_t)b * WINDOW;
  const int t = threadIdx.x;
  const int rr = t >> 4;
  const int cc = (t & 15) * 4;
  #pragma unroll
  for (int p = 0; p < 4; ++p) {
    int r = p * 16 + rr;
    *(uint2*)&tile[r][cc] = *(const uint2*)(Vb + (size_t)(j0 + r) * EMBED + e0 + cc);
  }
  __syncthreads();
  #pragma unroll
  for (int p = 0; p < 4; ++p) {
    int er = p * 16 + rr;
    ushort4 o;
    o.x = f2bf(bf2f(tile[cc + 0][er]) / Db[j0 + cc + 0]);
    o.y = f2bf(bf2f(tile[cc + 1][er]) / Db[j0 + cc + 1]);
    o.z = f2bf(bf2f(tile[cc + 2][er]) / Db[j0 + cc + 2]);
    o.w = f2bf(bf2f(tile[cc + 3][er]) / Db[j0 + cc + 3]);
    *(ushort4*)(Tb + (size_t)(e0 + er) * WINDOW + j0 + cc) = o;
  }
}

// ---- O = P * Vdt^T, XCD-pinned balanced grid (M-split, NO atomics):
// q 0..31:  it>=4 jobs split into 128-row halves on the rect core
//           (bottom rows +128: nt=4it+4; top: nt=4it+2); plain stores.
// q 32..47: it<=3 full 256^2 jobs (nt=4(it+1)).
// 48 jobs/XCD, longest first: makespan ~22-28 vs 32 K-tiles. ----
__global__ __launch_bounds__(512, 2) void k_out(
    const u16* __restrict__ P, const u16* __restrict__ Vdt, float* __restrict__ O)
{
  __shared__ u16 lds[8 * HALF2];
  const int s   = blockIdx.x;
  const int xcd = s & 7;
  const int q   = s >> 3;            // 0..47, descending cost order
  float* ObBase;
  const int lane = threadIdx.x & 63, wid = threadIdx.x >> 6;
  const int lrow = lane & 15, hi = lane >> 4;

  if (q < 32) {
    // ----- rect half-jobs: it = 7 - (q>>3); sub = q&7 -> half, et -----
    const int it  = 7 - (q >> 3);     // 7,6,5,4
    const int sub = q & 7;
    const int hb  = sub >> 2;         // 0 = bottom (rows +128, longer K), 1 = top
    const int et  = sub & 3;
    const int b   = (xcd - it) & 7;
    const int i0  = it * BM2 + (hb ? 0 : 128);
    const int e0  = et * BN2;
    const int nt  = hb ? (4 * it + 2) : (4 * it + 4);

    const u16* A = P   + (size_t)b * WINDOW * WINDOW + (size_t)i0 * WINDOW;
    const u16* B = Vdt + (size_t)b * EMBED * WINDOW  + (size_t)e0 * WINDOW;
    f32x4 acc[4][4];
    const f32x4 zz = {0.f,0.f,0.f,0.f};
    #pragma unroll
    for (int i = 0; i < 4; ++i) for (int j = 0; j < 4; ++j) acc[i][j] = zz;
    gemm_rect(A, WINDOW, B, WINDOW, nt, lds, acc);

    ObBase = O + (size_t)b * WINDOW * EMBED;
    const int wm = (wid >> 2) * 64, wn = (wid & 3) * 64;
    #pragma unroll
    for (int mi = 0; mi < 4; ++mi)
      #pragma unroll
      for (int ni = 0; ni < 4; ++ni)
        #pragma unroll
        for (int rr = 0; rr < 4; ++rr) {
          int gi = i0 + wm + mi * 16 + hi * 4 + rr;
          int ge = e0 + wn + ni * 16 + lrow;
          ObBase[(size_t)gi * EMBED + ge] = acc[mi][ni][rr];
        }
  } else {
    // ----- full jobs: it = 3 - ((q-32)>>2), et = (q-32)&3 -----
    const int qq = q - 32;            // 0..15
    const int it = 3 - (qq >> 2);     // 3,2,1,0
    const int et = qq & 3;
    const int b  = (xcd - it) & 7;
    const int i0 = it * BM2;
    const int e0 = et * BN2;

    const u16* A = P   + (size_t)b * WINDOW * WINDOW + (size_t)i0 * WINDOW;
    const u16* B = Vdt + (size_t)b * EMBED * WINDOW  + (size_t)e0 * WINDOW;
    f32x4 acc[8][4];
    const f32x4 zz = {0.f,0.f,0.f,0.f};
    #pragma unroll
    for (int i = 0; i < 8; ++i) for (int j = 0; j < 4; ++j) acc[i][j] = zz;
    gemm256(A, WINDOW, B, WINDOW, 4 * (it + 1), lds, acc);

    ObBase = O + (size_t)b * WINDOW * EMBED;
    const int wm = (wid >> 2) * 128, wn = (wid & 3) * 64;
    #pragma unroll
    for (int mi = 0; mi < 8; ++mi)
      #pragma unroll
      for (int ni = 0; ni < 4; ++ni)
        #pragma unroll
        for (int rr = 0; rr < 4; ++rr) {
          int gi = i0 + wm + mi * 16 + hi * 4 + rr;
          int ge = e0 + wn + ni * 16 + lrow;
          ObBase[(size_t)gi * EMBED + ge] = acc[mi][ni][rr];
        }
  }
}

extern "C" void kernel_launch(void* const* d_in, const int* in_sizes, int n_in,
                              void* d_out, int out_size, void* d_ws, size_t ws_size,
                              hipStream_t stream) {
  const float* X  = (const float*)d_in[0];
  const float* Wq = (const float*)d_in[1];
  const float* bq = (const float*)d_in[2];
  const float* Wk = (const float*)d_in[3];
  const float* bk = (const float*)d_in[4];
  const float* Wv = (const float*)d_in[5];
  const float* bv = (const float*)d_in[6];
  float* O = (float*)d_out;

  char* ws = (char*)d_ws;
  size_t off = 0;
  auto alloc = [&](size_t bytes) -> void* {
    void* p = ws + off; off += (bytes + 255) & ~(size_t)255; return p;
  };
  u16*  Xb  = (u16*)alloc((size_t)MTOT * EMBED * 2);
  u16*  Wb  = (u16*)alloc((size_t)3 * EMBED * EMBED * 2);
  u16*  Qb  = (u16*)alloc((size_t)MTOT * EMBED * 2);
  u16*  Kb  = (u16*)alloc((size_t)MTOT * EMBED * 2);          // pre-scaled by log2e/32
  u16*  Vb  = (u16*)alloc((size_t)MTOT * EMBED * 2);
  u16*  Vdt = (u16*)alloc((size_t)BATCH * EMBED * WINDOW * 2);
  u16*  P   = (u16*)alloc((size_t)BATCH * WINDOW * WINDOW * 2);
  float* D  = (float*)alloc((size_t)MTOT * 4);
  (void)ws_size; (void)in_sizes; (void)n_in; (void)out_size;

  // 0) fp32 -> bf16 converts (X; then all 3 W's in one launch)
  k_cvt<<<dim3((MTOT * EMBED / 4 + 255) / 256), 256, 0, stream>>>(X, Xb, MTOT * EMBED);
  k_cvtw<<<dim3(EMBED * EMBED / 4 / 256, 3), 256, 0, stream>>>(Wq, Wk, Wv, Wb);

  // 1) Q/K/V projections (768 blocks = 3 dispatch rounds)
  k_qkv<<<dim3(MTOT / BM2, EMBED / BN2, 3), 512, 0, stream>>>(Xb, Wb, bq, bk, bv, Qb, Kb, Vb);

  // 2) P = exp(QK^T/sqrt(E)) masked; D[j] = column sums (hybrid 320-job grid)
  (void)hipMemsetAsync(D, 0, (size_t)MTOT * 4, stream);
  k_spd<<<dim3(320), 512, 0, stream>>>(Qb, Kb, P, D);

  // 3) Vdt[e][j] = V[j][e] / D[j]
  k_vdt<<<dim3(WINDOW / 64, EMBED / 64, BATCH), 256, 0, stream>>>(Vb, D, Vdt);

  // 4) O = P * Vdt^T (384 balanced XCD-pinned jobs: rect M-split halves + fulls)
  k_out<<<dim3(384), 512, 0, stream>>>(P, Vdt, O);
}